// Round 2
// baseline (280.786 us; speedup 1.0000x reference)
//
#include <hip/hip_runtime.h>
#include <stdint.h>

#define HIDDEN 1024
#define BATCH  4
#define SEQ    2048
#define TOKENS (BATCH * SEQ)      // 8192
#define QKVD   (3 * HIDDEN)       // 3072

typedef unsigned short u16;
typedef __attribute__((ext_vector_type(8))) short   short8;   // 8 bf16 = 4 VGPRs
typedef __attribute__((ext_vector_type(4))) float   floatx4;

// deterministic round-to-nearest-even f32 -> bf16 (no NaN inputs here)
__device__ __forceinline__ u16 f32_bf16_rne(float f) {
    unsigned int u = __float_as_uint(f);
    u += 0x7FFFu + ((u >> 16) & 1u);
    return (u16)(u >> 16);
}

// async global->LDS, 16B per lane. LDS dest is wave-uniform base + lane*16.
__device__ __forceinline__ void gl16(const u16* g, u16* l) {
    __builtin_amdgcn_global_load_lds(
        (const __attribute__((address_space(1))) void*)g,
        (__attribute__((address_space(3))) void*)l, 16, 0, 0);
}

// End-of-K-step sync. vmcnt(8) = leave the 2 newest tiles' stages (2 tiles x
// 4 loads/wave) in flight; the oldest tile (needed next step) is guaranteed
// landed. vmcnt BEFORE barrier -> once all waves pass, ALL waves' loads for
// the next tile have landed. NEVER vmcnt(0) in the main loop (T4).
#define SYNC8() do { __builtin_amdgcn_sched_barrier(0); \
    asm volatile("s_waitcnt vmcnt(8)\n\ts_barrier" ::: "memory"); } while (0)

// ---------------------------------------------------------------- convert
// both input tensors in one launch (saves a dispatch gap)
__global__ __launch_bounds__(256) void cvt2_bf16_kernel(
        const float* __restrict__ sa, const float* __restrict__ sb,
        u16* __restrict__ da, u16* __restrict__ db, int n4a, int n4tot) {
    int i = blockIdx.x * 256 + threadIdx.x;
    if (i >= n4tot) return;
    float4 v;
    if (i < n4a) v = ((const float4*)sa)[i];
    else         v = ((const float4*)sb)[i - n4a];
    ushort4 o;
    o.x = f32_bf16_rne(v.x); o.y = f32_bf16_rne(v.y);
    o.z = f32_bf16_rne(v.z); o.w = f32_bf16_rne(v.w);
    if (i < n4a) ((ushort4*)da)[i] = o;
    else         ((ushort4*)db)[i - n4a] = o;
}

// ---------------------------------------------------------------- GEMM (NT)
// C[M,N] = A[M,K] * B[N,K]^T.  BM=BN=256, BK=32. 512 threads = 8 waves
// (2M x 4N), PER-WAVE 128x64 output = 8x4 grid of 16x16x32 bf16 MFMA.
//
// Round 8: wave tile 64x64 -> 128x64. Rounds 6 & 7 both pinned at
// MfmaUtil=32% with 0.5 ds_read_b128/MFMA (512 LDS B per MFMA); 128x64
// needs only 0.375 (12 reads per 32 MFMA: A 8 + B 4, B frags register-
// resident across both halves of the K-step).
//
// Pipeline: RING-4 LDS (4 x 32KB). While computing tile t (buf t&3), tile
// t+3 is staged into buf (t+3)&3 -> 2 full K-steps of staged-ahead data,
// loads never drained below 8 (SYNC8). One barrier per K-step.
//   step t: P0 { stage A(t+3) | read B0..3 + A0..3 | 16 MFMA (mi0..3) }
//           P1 { stage B(t+3) | read A4..7         | 16 MFMA (mi4..7) }
//           SYNC8
// Race-safety: stage target (t+3)&3 != read buf t&3 (3 != 0 mod 4); buffer
// reuse is separated by >=1 barrier; per-wave vmcnt(8) + barrier => every
// wave's loads for tile t+1 are visible to all before step t+1 reads.
//
// Slab layout (verified rounds 3-7, 0 bank conflicts): row = 64B, 16B slot
// XOR-swizzled phys = slot ^ ((row>>1)&3); staged linearly by gl16 with the
// inverse swizzle applied to the GLOBAL source address.
//
// EPI: 0 = bf16 store + bias[col]; 1 = f32 store * scale; 2 = f32 store.
template <int EPI>
__global__ __launch_bounds__(512, 2) void gemm_bt(
        const u16* __restrict__ A, const u16* __restrict__ B,
        void* __restrict__ Cv, const float* __restrict__ bias,
        int K, int lda, int ldb, int ldc,
        size_t sA, size_t sB, size_t sC, float scale) {
    // per buffer: A slab 8192 u16 (256 rows x 32k) + B slab 8192 u16 = 32 KB
    __shared__ __align__(16) u16 lds[4][16384];   // 128 KB

    const int t    = threadIdx.x;
    const int lane = t & 63;
    const int wid  = t >> 6;             // 0..7
    const int wr   = wid >> 2;           // 0..1  (M half, 128 rows each)
    const int wc   = wid & 3;            // 0..3  (N quarter, 64 cols each)
    const int bm   = blockIdx.y * 256;
    const int bn   = blockIdx.x * 256;

    const u16* Ab = A + (size_t)blockIdx.z * sA;
    const u16* Bb = B + (size_t)blockIdx.z * sB;

    // ---- staging source: thread t -> row t>>2 (and +128), phys slot t&3,
    // global slot = (t&3) ^ ((row>>1)&3)  (swizzle same for row and row+128)
    const int r0 = t >> 2;                              // 0..127
    const int sl = (t & 3) ^ ((r0 >> 1) & 3);
    const u16* gA0 = Ab + (size_t)(bm + r0) * lda + sl * 8;
    const u16* gA1 = gA0 + (size_t)128 * lda;
    const u16* gB0 = Bb + (size_t)(bn + r0) * ldb + sl * 8;
    const u16* gB1 = gB0 + (size_t)128 * ldb;

    // ---- fragment read geometry (verified 16x16x32 mappings)
    const int fr = lane & 15;            // row-in-16 of A/B fragment
    const int kc = lane >> 4;            // 16B k-chunk 0..3
    const int fo = ((kc ^ ((fr >> 1) & 3)) << 4);       // swizzled slot byte
    const int abyte = (wr * 128 + fr) * 64 + fo;          // into A slab
    const int bbyte = 16384 + (wc * 64 + fr) * 64 + fo;   // into B slab

    floatx4 acc[8][4];
#pragma unroll
    for (int i = 0; i < 8; i++)
#pragma unroll
        for (int j = 0; j < 4; j++) acc[i][j] = (floatx4){0.f, 0.f, 0.f, 0.f};

#define STAGE_A(p, scol) \
    gl16(gA0 + (scol), &lds[p][wid * 512]); \
    gl16(gA1 + (scol), &lds[p][4096 + wid * 512]);
#define STAGE_B(p, scol) \
    gl16(gB0 + (scol), &lds[p][8192  + wid * 512]); \
    gl16(gB1 + (scol), &lds[p][12288 + wid * 512]);

#define MF4(MI, AV) \
    acc[MI][0] = __builtin_amdgcn_mfma_f32_16x16x32_bf16(AV, b0, acc[MI][0], 0, 0, 0); \
    acc[MI][1] = __builtin_amdgcn_mfma_f32_16x16x32_bf16(AV, b1, acc[MI][1], 0, 0, 0); \
    acc[MI][2] = __builtin_amdgcn_mfma_f32_16x16x32_bf16(AV, b2, acc[MI][2], 0, 0, 0); \
    acc[MI][3] = __builtin_amdgcn_mfma_f32_16x16x32_bf16(AV, b3, acc[MI][3], 0, 0, 0);

#define STEP(q, p, scol) { \
    const char* base = (const char*)&lds[q][0]; \
    /* P0: stage A(t+3); read B frags + A lo; MFMA mi0..3 */ \
    STAGE_A(p, scol); \
    short8 b0 = *(const short8*)(base + bbyte); \
    short8 b1 = *(const short8*)(base + bbyte + 1024); \
    short8 b2 = *(const short8*)(base + bbyte + 2048); \
    short8 b3 = *(const short8*)(base + bbyte + 3072); \
    short8 a0 = *(const short8*)(base + abyte); \
    short8 a1 = *(const short8*)(base + abyte + 1024); \
    short8 a2 = *(const short8*)(base + abyte + 2048); \
    short8 a3 = *(const short8*)(base + abyte + 3072); \
    __builtin_amdgcn_s_setprio(1); \
    MF4(0, a0) MF4(1, a1) MF4(2, a2) MF4(3, a3) \
    __builtin_amdgcn_s_setprio(0); \
    /* P1: stage B(t+3); read A hi; MFMA mi4..7 (B frags reused) */ \
    STAGE_B(p, scol); \
    a0 = *(const short8*)(base + abyte + 4096); \
    a1 = *(const short8*)(base + abyte + 5120); \
    a2 = *(const short8*)(base + abyte + 6144); \
    a3 = *(const short8*)(base + abyte + 7168); \
    __builtin_amdgcn_s_setprio(1); \
    MF4(4, a0) MF4(5, a1) MF4(6, a2) MF4(7, a3) \
    __builtin_amdgcn_s_setprio(0); \
    SYNC8(); }

    // prologue: stage tiles 0,1,2 into bufs 0,1,2 (12 loads/wave);
    // vmcnt(8) -> tile 0 landed, tiles 1,2 in flight (= steady state).
    STAGE_A(0, 0)  STAGE_B(0, 0)
    STAGE_A(1, 32) STAGE_B(1, 32)
    STAGE_A(2, 64) STAGE_B(2, 64)
    SYNC8();

    const int nk = K >> 5;               // K-steps of 32 (32/32/64, all %4==0)
    for (int kt = 0; kt < nk; kt += 4) {
        const int s0 = (kt + 3 < nk ? kt + 3 : nk - 1) << 5;
        const int s1 = (kt + 4 < nk ? kt + 4 : nk - 1) << 5;
        const int s2 = (kt + 5 < nk ? kt + 5 : nk - 1) << 5;
        const int s3 = (kt + 6 < nk ? kt + 6 : nk - 1) << 5;
        STEP(0, 3, s0)
        STEP(1, 0, s1)
        STEP(2, 1, s2)
        STEP(3, 2, s3)
    }
    // drain dangling tail restages before the block retires
    asm volatile("s_waitcnt vmcnt(0)" ::: "memory");

#undef STEP
#undef MF4
#undef STAGE_A
#undef STAGE_B

    // epilogue: C/D 16x16 mapping col=lane&15, row=(lane>>4)*4+reg
    const int crow0 = bm + wr * 128 + kc * 4;
    const int ccol0 = bn + wc * 64 + fr;
    const size_t coff = (size_t)blockIdx.z * sC;

    if (EPI == 0) {
        u16* C = (u16*)Cv;
        float bv[4];
#pragma unroll
        for (int ni = 0; ni < 4; ni++) bv[ni] = bias[ccol0 + ni * 16];
#pragma unroll
        for (int mi = 0; mi < 8; mi++)
#pragma unroll
            for (int ni = 0; ni < 4; ni++)
#pragma unroll
                for (int r = 0; r < 4; r++)
                    C[coff + (size_t)(crow0 + mi * 16 + r) * ldc + (ccol0 + ni * 16)] =
                        f32_bf16_rne(acc[mi][ni][r] + bv[ni]);
    } else {
        float* C = (float*)Cv;
#pragma unroll
        for (int mi = 0; mi < 8; mi++)
#pragma unroll
            for (int ni = 0; ni < 4; ni++)
#pragma unroll
                for (int r = 0; r < 4; r++) {
                    float v = acc[mi][ni][r];
                    if (EPI == 1) v *= scale;
                    C[coff + (size_t)(crow0 + mi * 16 + r) * ldc + (ccol0 + ni * 16)] = v;
                }
    }
}

// ---------------------------------------------------------------- softmax
// one block per row; 2048 fp32 scores (already scaled) -> 2048 bf16 probs
__global__ __launch_bounds__(256) void softmax_kernel(
        const float* __restrict__ S, u16* __restrict__ P) {
    __shared__ float redm[4];
    __shared__ float reds[4];
    const size_t base = (size_t)blockIdx.x * SEQ;
    const int t = threadIdx.x, lane = t & 63, wid = t >> 6;
    const float4* src = (const float4*)(S + base);
    float4 a = src[t], b = src[t + 256];

    float m = fmaxf(fmaxf(fmaxf(a.x, a.y), fmaxf(a.z, a.w)),
                    fmaxf(fmaxf(b.x, b.y), fmaxf(b.z, b.w)));
#pragma unroll
    for (int off = 32; off; off >>= 1) m = fmaxf(m, __shfl_xor(m, off, 64));
    if (lane == 0) redm[wid] = m;
    __syncthreads();
    m = fmaxf(fmaxf(redm[0], redm[1]), fmaxf(redm[2], redm[3]));

    float e[8];
    e[0] = __expf(a.x - m); e[1] = __expf(a.y - m);
    e[2] = __expf(a.z - m); e[3] = __expf(a.w - m);
    e[4] = __expf(b.x - m); e[5] = __expf(b.y - m);
    e[6] = __expf(b.z - m); e[7] = __expf(b.w - m);
    float s = e[0] + e[1] + e[2] + e[3] + e[4] + e[5] + e[6] + e[7];
#pragma unroll
    for (int off = 32; off; off >>= 1) s += __shfl_xor(s, off, 64);
    if (lane == 0) reds[wid] = s;
    __syncthreads();
    s = reds[0] + reds[1] + reds[2] + reds[3];
    const float r = 1.f / s;

    ushort4* dst = (ushort4*)(P + base);
    ushort4 o0, o1;
    o0.x = f32_bf16_rne(e[0] * r); o0.y = f32_bf16_rne(e[1] * r);
    o0.z = f32_bf16_rne(e[2] * r); o0.w = f32_bf16_rne(e[3] * r);
    o1.x = f32_bf16_rne(e[4] * r); o1.y = f32_bf16_rne(e[5] * r);
    o1.z = f32_bf16_rne(e[6] * r); o1.w = f32_bf16_rne(e[7] * r);
    dst[t] = o0;
    dst[t + 256] = o1;
}

// ---------------------------------------------------------------- V transpose
// Vt[b][h][s] <- qkv[b*SEQ+s][2*HIDDEN+h], 64x64 LDS tiles, pad 66 (bank-safe)
__global__ __launch_bounds__(256) void transposeV_kernel(
        const u16* __restrict__ qkv, u16* __restrict__ Vt) {
    __shared__ u16 tile[64][66];
    const int b = blockIdx.z;
    const int s0 = blockIdx.x * 64, h0 = blockIdx.y * 64;
    const int t = threadIdx.x;
    const int c = t & 63, r4 = t >> 6;
#pragma unroll
    for (int i = 0; i < 16; i++) {
        int sl = i * 4 + r4;
        tile[sl][c] = qkv[(size_t)(b * SEQ + s0 + sl) * QKVD + 2 * HIDDEN + h0 + c];
    }
    __syncthreads();
#pragma unroll
    for (int i = 0; i < 16; i++) {
        int hl = i * 4 + r4;
        Vt[(size_t)(b * HIDDEN + h0 + hl) * SEQ + s0 + c] = tile[c][hl];
    }
}

// ---------------------------------------------------------------- launch
extern "C" void kernel_launch(void* const* d_in, const int* in_sizes, int n_in,
                              void* d_out, int out_size, void* d_ws, size_t ws_size,
                              hipStream_t stream) {
    const float* x    = (const float*)d_in[0];   // [4,2048,1024]
    const float* W    = (const float*)d_in[1];   // [3072,1024]
    const float* bias = (const float*)d_in[2];   // [3072]
    float* out = (float*)d_out;                  // [4,2048,1024]

    // workspace layout (191 MB total)
    u16* Xb  = (u16*)d_ws;                                  // 8192x1024 bf16
    u16* Wb  = Xb + (size_t)TOKENS * HIDDEN;                // 3072x1024 bf16
    u16* qkv = Wb + (size_t)QKVD * HIDDEN;                  // 8192x3072 bf16
    float* scores = (float*)(qkv + (size_t)TOKENS * QKVD);  // 4x2048x2048 f32
    u16* P  = (u16*)(scores + (size_t)BATCH * SEQ * SEQ);   // 4x2048x2048 bf16
    u16* Vt = P + (size_t)BATCH * SEQ * SEQ;                // 4x1024x2048 bf16

    // 1) fp32 -> bf16 casts (both tensors, one launch)
    {
        const int n4a = TOKENS * HIDDEN / 4;                // 2097152
        const int n4b = QKVD * HIDDEN / 4;                  // 786432
        const int n4t = n4a + n4b;
        cvt2_bf16_kernel<<<(n4t + 255) / 256, 256, 0, stream>>>(x, W, Xb, Wb, n4a, n4t);
    }

    // 2) QKV projection: qkv = Xb @ Wb^T + bias  (bf16 out)  grid 12x32 = 384
    gemm_bt<0><<<dim3(QKVD / 256, TOKENS / 256, 1), 512, 0, stream>>>(
        Xb, Wb, qkv, bias, HIDDEN, HIDDEN, HIDDEN, QKVD, 0, 0, 0, 1.f);

    // 3) scores = scale * Q @ K^T per batch (f32 out)  grid 8x8x4 = 256
    gemm_bt<1><<<dim3(SEQ / 256, SEQ / 256, BATCH), 512, 0, stream>>>(
        qkv, qkv + HIDDEN, scores, nullptr, HIDDEN, QKVD, QKVD, SEQ,
        (size_t)SEQ * QKVD, (size_t)SEQ * QKVD, (size_t)SEQ * SEQ, 0.03125f);

    // 4) row softmax -> bf16 P
    softmax_kernel<<<BATCH * SEQ, 256, 0, stream>>>(scores, P);

    // 5) V transpose (bias already folded in step 2)
    transposeV_kernel<<<dim3(SEQ / 64, HIDDEN / 64, BATCH), 256, 0, stream>>>(qkv, Vt);

    // 6) out = P @ Vt^T per batch (f32 out)  grid 4x8x4 = 128
    gemm_bt<2><<<dim3(HIDDEN / 256, SEQ / 256, BATCH), 512, 0, stream>>>(
        P, Vt, out, nullptr, SEQ, SEQ, SEQ, HIDDEN,
        (size_t)SEQ * SEQ, (size_t)HIDDEN * SEQ, (size_t)SEQ * HIDDEN, 1.f);
}

// Round 3
// 258.173 us; speedup vs baseline: 1.0876x; 1.0876x over previous
//
#include <hip/hip_runtime.h>
#include <stdint.h>

#define HIDDEN 1024
#define BATCH  4
#define SEQ    2048
#define TOKENS (BATCH * SEQ)      // 8192
#define QKVD   (3 * HIDDEN)       // 3072

typedef unsigned short u16;
typedef __attribute__((ext_vector_type(8))) short   short8;   // 8 bf16 = 4 VGPRs
typedef __attribute__((ext_vector_type(4))) float   floatx4;

// deterministic round-to-nearest-even f32 -> bf16 (no NaN inputs here)
__device__ __forceinline__ u16 f32_bf16_rne(float f) {
    unsigned int u = __float_as_uint(f);
    u += 0x7FFFu + ((u >> 16) & 1u);
    return (u16)(u >> 16);
}

// async global->LDS, 16B per lane. LDS dest is wave-uniform base + lane*16.
__device__ __forceinline__ void gl16(const u16* g, u16* l) {
    __builtin_amdgcn_global_load_lds(
        (const __attribute__((address_space(1))) void*)g,
        (__attribute__((address_space(3))) void*)l, 16, 0, 0);
}

// phase barrier: sched_barrier(0) pins ALL instruction motion (incl. MFMA,
// which a "memory" clobber alone does not order - rule #18), then raw barrier.
#define PBAR() do { __builtin_amdgcn_sched_barrier(0); \
    asm volatile("s_barrier" ::: "memory"); } while (0)
#define LG0() asm volatile("s_waitcnt lgkmcnt(0)" ::: "memory")
// counted vmcnt: leave the 4 newest staging loads in flight (NEVER 0 in-loop)
#define VM4() do { __builtin_amdgcn_sched_barrier(0); \
    asm volatile("s_waitcnt vmcnt(4)" ::: "memory"); } while (0)

// ---------------------------------------------------------------- convert
__global__ __launch_bounds__(256) void cvt2_bf16_kernel(
        const float* __restrict__ sa, const float* __restrict__ sb,
        u16* __restrict__ da, u16* __restrict__ db, int n4a, int n4tot) {
    int i = blockIdx.x * 256 + threadIdx.x;
    if (i >= n4tot) return;
    float4 v;
    if (i < n4a) v = ((const float4*)sa)[i];
    else         v = ((const float4*)sb)[i - n4a];
    ushort4 o;
    o.x = f32_bf16_rne(v.x); o.y = f32_bf16_rne(v.y);
    o.z = f32_bf16_rne(v.z); o.w = f32_bf16_rne(v.w);
    if (i < n4a) ((ushort4*)da)[i] = o;
    else         ((ushort4*)db)[i - n4a] = o;
}

// ---------------------------------------------------------------- GEMM (NT)
// C[M,N] = A[M,K]*B[N,K]^T.  Faithful port of the m201 8-phase template.
// BM = 2*WM (WM=128 -> 256x256 tile; WM=64 -> 128x256), BN=256, BK=64.
// 512 threads = 8 waves (2M x 4N), per-wave WM x 64 output.
//
// LDS: 2 buffers, each = [A_ks0 | A_ks1 | B_ks0 | B_ks1] slabs.
// Slab = rows x 32k, row = 64 B = 4 x 16B slots, phys slot = slot^((row>>1)&3)
// (verified 0 bank conflicts rounds 3-8); staged linearly by global_load_lds
// with the inverse swizzle applied to the GLOBAL source address.
//
// 8 phases per iter (2 K-tiles T=buf0, T+1=buf1), per phase:
//   { ds_read subtile ; stage 1 slab ; PBAR ; lgkmcnt(0) ; setprio(1) ;
//     16(8) MFMA ; setprio(0) ; PBAR }
// Stage targets: ph1: A0(T+1)->b1  ph2: A1(T+1)->b1  ph3: B0(T+2)->b0
//  ph4: B1(T+2)->b0 [vmcnt4]  ph5: A0(T+2)->b0  ph6: A1(T+2)->b0
//  ph7: B0(T+3)->b1  ph8: B1(T+3)->b1 [vmcnt4]
// Race proof: a slab region's last ds_read drains at its phase's own MFMA
// waits (all reads feed that phase's MFMAs), >=1 barrier before the
// overwriting gl16 issues (A slabs read ph1&ph3 -> staged ph5+; B slabs read
// ph1&ph2 -> staged ph3+; other-buf slabs idle). vmcnt(4) FIFO argument:
// at ph4 the 4 in-flight loads are B(T+2) -> A(T+1) landed before ph5 reads;
// at ph8 they are B(T+3) -> A(T+2)+B(T+2) landed before next-iter ph1 reads.
//
// EPI: 0 = bf16 store + bias[col]; 1 = f32 store * scale; 2 = f32 store.
template <int EPI, int WM>
__global__ __launch_bounds__(512, 2) void gemm_bt(
        const u16* __restrict__ A, const u16* __restrict__ B,
        void* __restrict__ Cv, const float* __restrict__ bias,
        int K, int lda, int ldb, int ldc,
        size_t sA, size_t sB, size_t sC, float scale) {
    constexpr int BM    = 2 * WM;
    constexpr int MIH   = WM / 32;          // mi frags per half-phase (4 or 2)
    constexpr int ASLAB = BM * 64;          // bytes per A k-slab
    constexpr int BSLAB = 256 * 64;         // bytes per B k-slab (16 KB)
    constexpr int BUFB  = 2 * ASLAB + 2 * BSLAB;
    __shared__ __align__(16) char lds[2][BUFB];   // 128 KB (WM=128) / 96 KB

    const int t    = threadIdx.x;
    const int lane = t & 63;
    const int wid  = t >> 6;             // 0..7
    const int wr   = wid >> 2;           // 0..1  (M half)
    const int wc   = wid & 3;            // 0..3  (N quarter, 64 cols)
    const int bm   = blockIdx.y * BM;
    const int bn   = blockIdx.x * 256;

    const u16* Ab = A + (size_t)blockIdx.z * sA;
    const u16* Bb = B + (size_t)blockIdx.z * sB;

    // staging source: thread t -> row t>>2 (+128), phys slot t&3,
    // global slot = (t&3) ^ ((row>>1)&3)   (same swizzle for row+128)
    const int r0 = t >> 2;
    const int sl = (t & 3) ^ ((r0 >> 1) & 3);
    const u16* gA0 = Ab + (size_t)(bm + r0) * lda + sl * 8;
    const u16* gA1 = gA0 + (size_t)128 * lda;          // used when WM==128
    const u16* gB0 = Bb + (size_t)(bn + r0) * ldb + sl * 8;
    const u16* gB1 = gB0 + (size_t)128 * ldb;

    // fragment read geometry (verified 16x16x32 mappings)
    const int fr  = lane & 15;
    const int kc  = lane >> 4;
    const int frb = fr * 64 + ((kc ^ ((fr >> 1) & 3)) << 4);

    floatx4 acc[2 * MIH][4];
#pragma unroll
    for (int i = 0; i < 2 * MIH; i++)
#pragma unroll
        for (int j = 0; j < 4; j++) acc[i][j] = (floatx4){0.f, 0.f, 0.f, 0.f};

    short8 aF[MIH][2], bLo[2][2], bHi[2][2];

    auto rdA = [&](short8 (&dst)[MIH][2], const char* bp, int miBase) {
#pragma unroll
        for (int m = 0; m < MIH; m++)
#pragma unroll
            for (int ks = 0; ks < 2; ks++)
                dst[m][ks] = *(const short8*)(bp + ks * ASLAB +
                    (wr * WM + (miBase + m) * 16) * 64 + frb);
    };
    auto rdB = [&](short8 (&dst)[2][2], const char* bp, int niBase) {
#pragma unroll
        for (int n = 0; n < 2; n++)
#pragma unroll
            for (int ks = 0; ks < 2; ks++)
                dst[n][ks] = *(const short8*)(bp + 2 * ASLAB + ks * BSLAB +
                    (wc * 64 + (niBase + n) * 16) * 64 + frb);
    };
    auto mf = [&](short8 (&av)[MIH][2], short8 (&bv)[2][2], int miB, int niB) {
        __builtin_amdgcn_s_setprio(1);
#pragma unroll
        for (int m = 0; m < MIH; m++)
#pragma unroll
            for (int n = 0; n < 2; n++)
#pragma unroll
                for (int ks = 0; ks < 2; ks++)
                    acc[miB + m][niB + n] = __builtin_amdgcn_mfma_f32_16x16x32_bf16(
                        av[m][ks], bv[n][ks], acc[miB + m][niB + n], 0, 0, 0);
        __builtin_amdgcn_s_setprio(0);
    };

#define STA(buf, ks, sc) do { \
    char* d = &lds[buf][(ks) * ASLAB] + wid * 1024; \
    gl16(gA0 + (sc) + (ks) * 32, (u16*)d); \
    if constexpr (WM == 128) gl16(gA1 + (sc) + (ks) * 32, (u16*)(d + 8192)); \
  } while (0)
#define STB(buf, ks, sc) do { \
    char* d = &lds[buf][2 * ASLAB + (ks) * BSLAB] + wid * 1024; \
    gl16(gB0 + (sc) + (ks) * 32, (u16*)d); \
    gl16(gB1 + (sc) + (ks) * 32, (u16*)(d + 8192)); \
  } while (0)

// one K-tile = 4 phases; reads first, then stage, double barrier around MFMA
#define GROUP(q, S1, S2, S3, S4) { \
    const char* bp = &lds[q][0]; \
    rdA(aF, bp, 0); rdB(bLo, bp, 0); S1; PBAR(); LG0(); \
    mf(aF, bLo, 0, 0);   PBAR(); \
    rdB(bHi, bp, 2);                S2; PBAR(); LG0(); \
    mf(aF, bHi, 0, 2);   PBAR(); \
    rdA(aF, bp, MIH);               S3; PBAR(); LG0(); \
    mf(aF, bHi, MIH, 2); PBAR(); \
    S4; VM4(); PBAR(); \
    mf(aF, bLo, MIH, 0); PBAR(); \
}

    // prologue: tile0 all slabs -> buf0, tile1 B slabs -> buf1 (A(1) comes in
    // ph1-2).  vmcnt(4) -> tile0 landed, B(1) (4 loads) in flight.
    STA(0, 0, 0); STA(0, 1, 0); STB(0, 0, 0); STB(0, 1, 0);
    STB(1, 0, 64); STB(1, 1, 64);
    VM4(); PBAR();

    const int nk = K >> 6;               // 64-wide K-tiles (16 or 32), even
    for (int T = 0; T < nk; T += 2) {
        const int c1 = (T + 1) << 6;
        const int c2 = (T + 2 < nk ? T + 2 : nk - 1) << 6;   // tail clamp
        const int c3 = (T + 3 < nk ? T + 3 : nk - 1) << 6;
        GROUP(0, STA(1, 0, c1), STA(1, 1, c1), STB(0, 0, c2), STB(0, 1, c2))
        GROUP(1, STA(0, 0, c2), STA(0, 1, c2), STB(1, 0, c3), STB(1, 1, c3))
    }
    asm volatile("s_waitcnt vmcnt(0)" ::: "memory");   // drain tail restages

#undef GROUP
#undef STB
#undef STA

    // epilogue: C/D 16x16 mapping col=lane&15, row=(lane>>4)*4+reg
    const int crow0 = bm + wr * WM + kc * 4;
    const int ccol0 = bn + wc * 64 + fr;
    const size_t coff = (size_t)blockIdx.z * sC;

    if (EPI == 0) {
        u16* C = (u16*)Cv;
        float bv[4];
#pragma unroll
        for (int ni = 0; ni < 4; ni++) bv[ni] = bias[ccol0 + ni * 16];
#pragma unroll
        for (int mi = 0; mi < 2 * MIH; mi++)
#pragma unroll
            for (int ni = 0; ni < 4; ni++)
#pragma unroll
                for (int r = 0; r < 4; r++)
                    C[coff + (size_t)(crow0 + mi * 16 + r) * ldc + (ccol0 + ni * 16)] =
                        f32_bf16_rne(acc[mi][ni][r] + bv[ni]);
    } else {
        float* C = (float*)Cv;
#pragma unroll
        for (int mi = 0; mi < 2 * MIH; mi++)
#pragma unroll
            for (int ni = 0; ni < 4; ni++)
#pragma unroll
                for (int r = 0; r < 4; r++) {
                    float v = acc[mi][ni][r];
                    if (EPI == 1) v *= scale;
                    C[coff + (size_t)(crow0 + mi * 16 + r) * ldc + (ccol0 + ni * 16)] = v;
                }
    }
}

// ---------------------------------------------------------------- softmax
// one block per row; 2048 fp32 scores (already scaled) -> 2048 bf16 probs
__global__ __launch_bounds__(256) void softmax_kernel(
        const float* __restrict__ S, u16* __restrict__ P) {
    __shared__ float redm[4];
    __shared__ float reds[4];
    const size_t base = (size_t)blockIdx.x * SEQ;
    const int t = threadIdx.x, lane = t & 63, wid = t >> 6;
    const float4* src = (const float4*)(S + base);
    float4 a = src[t], b = src[t + 256];

    float m = fmaxf(fmaxf(fmaxf(a.x, a.y), fmaxf(a.z, a.w)),
                    fmaxf(fmaxf(b.x, b.y), fmaxf(b.z, b.w)));
#pragma unroll
    for (int off = 32; off; off >>= 1) m = fmaxf(m, __shfl_xor(m, off, 64));
    if (lane == 0) redm[wid] = m;
    __syncthreads();
    m = fmaxf(fmaxf(redm[0], redm[1]), fmaxf(redm[2], redm[3]));

    float e[8];
    e[0] = __expf(a.x - m); e[1] = __expf(a.y - m);
    e[2] = __expf(a.z - m); e[3] = __expf(a.w - m);
    e[4] = __expf(b.x - m); e[5] = __expf(b.y - m);
    e[6] = __expf(b.z - m); e[7] = __expf(b.w - m);
    float s = e[0] + e[1] + e[2] + e[3] + e[4] + e[5] + e[6] + e[7];
#pragma unroll
    for (int off = 32; off; off >>= 1) s += __shfl_xor(s, off, 64);
    if (lane == 0) reds[wid] = s;
    __syncthreads();
    s = reds[0] + reds[1] + reds[2] + reds[3];
    const float r = 1.f / s;

    ushort4* dst = (ushort4*)(P + base);
    ushort4 o0, o1;
    o0.x = f32_bf16_rne(e[0] * r); o0.y = f32_bf16_rne(e[1] * r);
    o0.z = f32_bf16_rne(e[2] * r); o0.w = f32_bf16_rne(e[3] * r);
    o1.x = f32_bf16_rne(e[4] * r); o1.y = f32_bf16_rne(e[5] * r);
    o1.z = f32_bf16_rne(e[6] * r); o1.w = f32_bf16_rne(e[7] * r);
    dst[t] = o0;
    dst[t + 256] = o1;
}

// ---------------------------------------------------------------- V transpose
// Vt[b][h][s] <- qkv[b*SEQ+s][2*HIDDEN+h], 64x64 LDS tiles, pad 66 (bank-safe)
__global__ __launch_bounds__(256) void transposeV_kernel(
        const u16* __restrict__ qkv, u16* __restrict__ Vt) {
    __shared__ u16 tile[64][66];
    const int b = blockIdx.z;
    const int s0 = blockIdx.x * 64, h0 = blockIdx.y * 64;
    const int t = threadIdx.x;
    const int c = t & 63, r4 = t >> 6;
#pragma unroll
    for (int i = 0; i < 16; i++) {
        int sl = i * 4 + r4;
        tile[sl][c] = qkv[(size_t)(b * SEQ + s0 + sl) * QKVD + 2 * HIDDEN + h0 + c];
    }
    __syncthreads();
#pragma unroll
    for (int i = 0; i < 16; i++) {
        int hl = i * 4 + r4;
        Vt[(size_t)(b * HIDDEN + h0 + hl) * SEQ + s0 + c] = tile[c][hl];
    }
}

// ---------------------------------------------------------------- launch
extern "C" void kernel_launch(void* const* d_in, const int* in_sizes, int n_in,
                              void* d_out, int out_size, void* d_ws, size_t ws_size,
                              hipStream_t stream) {
    const float* x    = (const float*)d_in[0];   // [4,2048,1024]
    const float* W    = (const float*)d_in[1];   // [3072,1024]
    const float* bias = (const float*)d_in[2];   // [3072]
    float* out = (float*)d_out;                  // [4,2048,1024]

    // workspace layout (191 MB total)
    u16* Xb  = (u16*)d_ws;                                  // 8192x1024 bf16
    u16* Wb  = Xb + (size_t)TOKENS * HIDDEN;                // 3072x1024 bf16
    u16* qkv = Wb + (size_t)QKVD * HIDDEN;                  // 8192x3072 bf16
    float* scores = (float*)(qkv + (size_t)TOKENS * QKVD);  // 4x2048x2048 f32
    u16* P  = (u16*)(scores + (size_t)BATCH * SEQ * SEQ);   // 4x2048x2048 bf16
    u16* Vt = P + (size_t)BATCH * SEQ * SEQ;                // 4x1024x2048 bf16

    // 1) fp32 -> bf16 casts (both tensors, one launch)
    {
        const int n4a = TOKENS * HIDDEN / 4;
        const int n4b = QKVD * HIDDEN / 4;
        const int n4t = n4a + n4b;
        cvt2_bf16_kernel<<<(n4t + 255) / 256, 256, 0, stream>>>(x, W, Xb, Wb, n4a, n4t);
    }

    // 2) QKV projection: qkv = Xb @ Wb^T + bias (bf16 out)  grid 12x32 = 384
    gemm_bt<0, 128><<<dim3(QKVD / 256, TOKENS / 256, 1), 512, 0, stream>>>(
        Xb, Wb, qkv, bias, HIDDEN, HIDDEN, HIDDEN, QKVD, 0, 0, 0, 1.f);

    // 3) scores = scale * Q @ K^T per batch (f32 out)  grid 8x8x4 = 256
    gemm_bt<1, 128><<<dim3(SEQ / 256, SEQ / 256, BATCH), 512, 0, stream>>>(
        qkv, qkv + HIDDEN, scores, nullptr, HIDDEN, QKVD, QKVD, SEQ,
        (size_t)SEQ * QKVD, (size_t)SEQ * QKVD, (size_t)SEQ * SEQ, 0.03125f);

    // 4) row softmax -> bf16 P
    softmax_kernel<<<BATCH * SEQ, 256, 0, stream>>>(scores, P);

    // 5) V transpose (bias already folded in step 2)
    transposeV_kernel<<<dim3(SEQ / 64, HIDDEN / 64, BATCH), 256, 0, stream>>>(qkv, Vt);

    // 6) out = P @ Vt^T per batch (f32 out)  WM=64 variant: grid 4x16x4 = 256
    gemm_bt<2, 64><<<dim3(HIDDEN / 256, SEQ / 128, BATCH), 512, 0, stream>>>(
        P, Vt, out, nullptr, SEQ, SEQ, SEQ, HIDDEN,
        (size_t)SEQ * SEQ, (size_t)HIDDEN * SEQ, (size_t)SEQ * HIDDEN, 1.f);
}